// Round 1
// baseline (1329.442 us; speedup 1.0000x reference)
//
#include <hip/hip_runtime.h>
#include <math.h>

#define B_   2
#define N_   8000
#define C_   512
#define NH   8
#define HD   64
#define DD   20
#define DR   10
#define NSR  1000
#define C2   1024
#define EPSF 1e-6f

// ---------------- SGEMM with bias: C[M,N] = A[M,K] @ B[K,N] + bias[N] ----------------
// 64x64 block tile, K-step 16, 256 threads, 4x4 acc per thread.
__global__ __launch_bounds__(256) void sgemm_bias(
    const float* __restrict__ A, const float* __restrict__ Bm,
    const float* __restrict__ bias, float* __restrict__ Cm,
    int M, int Nn, int K) {
  __shared__ float As[16][65];  // [k][m], +1 pad -> <=2-way bank aliasing (free)
  __shared__ float Bs[16][65];  // [k][n]
  const int tid = threadIdx.x;
  const int bm = blockIdx.x * 64, bn = blockIdx.y * 64;
  const int tx = tid & 15, ty = tid >> 4;
  float acc[4][4] = {};
  for (int k0 = 0; k0 < K; k0 += 16) {
    #pragma unroll
    for (int i = 0; i < 4; ++i) {
      int r = (tid >> 4) + 16 * i;
      int row = bm + r;
      float v = 0.f;
      if (row < M) v = A[(size_t)row * K + k0 + (tid & 15)];
      As[tid & 15][r] = v;
    }
    #pragma unroll
    for (int i = 0; i < 4; ++i) {
      int k = (tid >> 6) + 4 * i;
      int n = tid & 63;
      Bs[k][n] = Bm[(size_t)(k0 + k) * Nn + bn + n];
    }
    __syncthreads();
    #pragma unroll
    for (int k = 0; k < 16; ++k) {
      float a[4], b[4];
      #pragma unroll
      for (int i = 0; i < 4; ++i) a[i] = As[k][ty * 4 + i];
      #pragma unroll
      for (int j = 0; j < 4; ++j) b[j] = Bs[k][tx * 4 + j];
      #pragma unroll
      for (int i = 0; i < 4; ++i)
        #pragma unroll
        for (int j = 0; j < 4; ++j)
          acc[i][j] = fmaf(a[i], b[j], acc[i][j]);
    }
    __syncthreads();
  }
  #pragma unroll
  for (int i = 0; i < 4; ++i) {
    int row = bm + ty * 4 + i;
    if (row >= M) continue;
    #pragma unroll
    for (int j = 0; j < 4; ++j) {
      int col = bn + tx * 4 + j;
      Cm[(size_t)row * Nn + col] = acc[i][j] + bias[col];
    }
  }
}

// ---------------- depthwise conv3d k3 s2 p1 + bias + LayerNorm ----------------
// grid = B*NSR rows, block = 512 (one thread per channel)
__global__ __launch_bounds__(512) void conv_ln_kernel(
    const float* __restrict__ x, const float* __restrict__ sr_w,
    const float* __restrict__ sr_b, const float* __restrict__ sr_g,
    const float* __restrict__ sr_beta, float* __restrict__ xr_ln) {
  const int row = blockIdx.x;           // b*NSR + m
  const int b = row / NSR, m = row % NSR;
  const int dr = m / 100, hr = (m / 10) % 10, wr = m % 10;
  const int c = threadIdx.x;
  float acc = 0.f;
  #pragma unroll
  for (int kd = 0; kd < 3; ++kd) {
    int din = 2 * dr + kd - 1;
    if (din < 0 || din >= DD) continue;
    #pragma unroll
    for (int kh = 0; kh < 3; ++kh) {
      int hin = 2 * hr + kh - 1;
      if (hin < 0 || hin >= DD) continue;
      #pragma unroll
      for (int kw = 0; kw < 3; ++kw) {
        int win = 2 * wr + kw - 1;
        if (win < 0 || win >= DD) continue;
        int nin = (din * DD + hin) * DD + win;
        acc = fmaf(x[((size_t)b * N_ + nin) * C_ + c],
                   sr_w[c * 27 + kd * 9 + kh * 3 + kw], acc);
      }
    }
  }
  acc += sr_b[c];
  // block LayerNorm over 512
  float s1 = acc, s2 = acc * acc;
  #pragma unroll
  for (int off = 32; off > 0; off >>= 1) {
    s1 += __shfl_xor(s1, off, 64);
    s2 += __shfl_xor(s2, off, 64);
  }
  __shared__ float ws1[8], ws2[8];
  const int wid = threadIdx.x >> 6, lid = threadIdx.x & 63;
  if (lid == 0) { ws1[wid] = s1; ws2[wid] = s2; }
  __syncthreads();
  float t1 = 0.f, t2 = 0.f;
  #pragma unroll
  for (int i = 0; i < 8; ++i) { t1 += ws1[i]; t2 += ws2[i]; }
  float mean = t1 * (1.f / C_);
  float var = t2 * (1.f / C_) - mean * mean;
  float r = rsqrtf(var + EPSF);
  xr_ln[(size_t)row * C_ + c] = (acc - mean) * r * sr_g[c] + sr_beta[c];
}

// ---------------- attention: one thread per query row, online softmax ----------------
// grid = (ceil(N/256), B*NH), block 256. KV layout: (B, NSR, 2C); k at [h*64+d], v at [512+h*64+d]
__global__ __launch_bounds__(256) void attn_kernel(
    const float* __restrict__ Q, const float* __restrict__ KV,
    float* __restrict__ O) {
  const int bh = blockIdx.y;
  const int b = bh >> 3, h = bh & 7;
  const int n = blockIdx.x * 256 + threadIdx.x;
  const bool active = (n < N_);
  __shared__ float kbuf[64][HD];
  __shared__ float vbuf[64][HD];

  const float* qptr = Q + ((size_t)b * N_ + (active ? n : 0)) * C_ + h * HD;
  float q[HD];
  #pragma unroll
  for (int d = 0; d < HD; d += 4) {
    float4 t = *(const float4*)(qptr + d);
    q[d] = t.x; q[d + 1] = t.y; q[d + 2] = t.z; q[d + 3] = t.w;
  }
  float o[HD];
  #pragma unroll
  for (int d = 0; d < HD; ++d) o[d] = 0.f;
  float mrun = -1e30f, lrun = 0.f;

  for (int t0 = 0; t0 < NSR; t0 += 64) {
    const int nrow = min(64, NSR - t0);
    __syncthreads();
    for (int i = threadIdx.x; i < 64 * HD; i += 256) {
      int mm = i >> 6, d = i & 63;
      if (mm < nrow) {
        const float* kvrow = KV + ((size_t)b * NSR + t0 + mm) * C2 + h * HD + d;
        kbuf[mm][d] = kvrow[0];
        vbuf[mm][d] = kvrow[C_];
      }
    }
    __syncthreads();
    if (active) {
      for (int mm = 0; mm < nrow; ++mm) {
        float s = 0.f;
        #pragma unroll
        for (int d = 0; d < HD; ++d) s = fmaf(q[d], kbuf[mm][d], s);
        s *= 0.125f;  // hd^-0.5
        if (s > mrun) {
          float corr = __expf(mrun - s);
          lrun *= corr;
          #pragma unroll
          for (int d = 0; d < HD; ++d) o[d] *= corr;
          mrun = s;
        }
        float p = __expf(s - mrun);
        lrun += p;
        #pragma unroll
        for (int d = 0; d < HD; ++d) o[d] = fmaf(p, vbuf[mm][d], o[d]);
      }
    }
  }
  if (active) {
    float inv = 1.f / lrun;
    float* optr = O + ((size_t)b * N_ + n) * C_ + h * HD;
    #pragma unroll
    for (int d = 0; d < HD; d += 4) {
      float4 t;
      t.x = o[d] * inv; t.y = o[d + 1] * inv; t.z = o[d + 2] * inv; t.w = o[d + 3] * inv;
      *(float4*)(optr + d) = t;
    }
  }
}

// ---------------- trilinear upsample of v (heads-major = KV v part) + LN + add into O ----------------
// grid = B*N rows, block 512 (one thread per channel)
__global__ __launch_bounds__(512) void ident_ln_add_kernel(
    const float* __restrict__ KV, const float* __restrict__ up_g,
    const float* __restrict__ up_beta, float* __restrict__ O) {
  const int row = blockIdx.x;           // b*N + n
  const int b = row / N_, n = row % N_;
  const int od = n / 400, oh = (n / 20) % 20, ow = n % 20;

  // half-pixel trilinear, scale 2: o=2t -> (t-1,t) w=(0.25,0.75); o=2t+1 -> (t,t+1) w=(0.75,0.25); clamped
  int i0[3], i1[3]; float w0[3], w1[3];
  int oo[3] = {od, oh, ow};
  #pragma unroll
  for (int a = 0; a < 3; ++a) {
    int t = oo[a] >> 1;
    if (oo[a] & 1) { i0[a] = t; i1[a] = (t + 1 < DR) ? t + 1 : DR - 1; w0[a] = 0.75f; w1[a] = 0.25f; }
    else           { i0[a] = (t - 1 >= 0) ? t - 1 : 0; i1[a] = t;      w0[a] = 0.25f; w1[a] = 0.75f; }
  }
  const int c = threadIdx.x;
  float val = 0.f;
  #pragma unroll
  for (int jd = 0; jd < 2; ++jd) {
    int id = jd ? i1[0] : i0[0]; float wd = jd ? w1[0] : w0[0];
    #pragma unroll
    for (int jh = 0; jh < 2; ++jh) {
      int ih = jh ? i1[1] : i0[1]; float wh = jh ? w1[1] : w0[1];
      #pragma unroll
      for (int jw = 0; jw < 2; ++jw) {
        int iw = jw ? i1[2] : i0[2]; float ww = jw ? w1[2] : w0[2];
        int mm = (id * DR + ih) * DR + iw;
        val = fmaf(wd * wh * ww, KV[((size_t)b * NSR + mm) * C2 + C_ + c], val);
      }
    }
  }
  // block LayerNorm over 512
  float s1 = val, s2 = val * val;
  #pragma unroll
  for (int off = 32; off > 0; off >>= 1) {
    s1 += __shfl_xor(s1, off, 64);
    s2 += __shfl_xor(s2, off, 64);
  }
  __shared__ float ws1[8], ws2[8];
  const int wid = threadIdx.x >> 6, lid = threadIdx.x & 63;
  if (lid == 0) { ws1[wid] = s1; ws2[wid] = s2; }
  __syncthreads();
  float t1 = 0.f, t2 = 0.f;
  #pragma unroll
  for (int i = 0; i < 8; ++i) { t1 += ws1[i]; t2 += ws2[i]; }
  float mean = t1 * (1.f / C_);
  float var = t2 * (1.f / C_) - mean * mean;
  float r = rsqrtf(var + EPSF);
  O[(size_t)row * C_ + c] += (val - mean) * r * up_g[c] + up_beta[c];
}

extern "C" void kernel_launch(void* const* d_in, const int* in_sizes, int n_in,
                              void* d_out, int out_size, void* d_ws, size_t ws_size,
                              hipStream_t stream) {
  (void)in_sizes; (void)n_in; (void)out_size; (void)ws_size;
  const float* x       = (const float*)d_in[0];
  const float* Wq      = (const float*)d_in[1];
  const float* bq      = (const float*)d_in[2];
  const float* Wkv     = (const float*)d_in[3];
  const float* bkv     = (const float*)d_in[4];
  const float* sr_w    = (const float*)d_in[5];
  const float* sr_b    = (const float*)d_in[6];
  const float* sr_g    = (const float*)d_in[7];
  const float* sr_beta = (const float*)d_in[8];
  const float* up_g    = (const float*)d_in[9];
  const float* up_beta = (const float*)d_in[10];
  const float* Wp      = (const float*)d_in[11];
  const float* bp      = (const float*)d_in[12];
  float* out = (float*)d_out;

  float* Q   = (float*)d_ws;                    // B*N*C     = 8,192,000 f
  float* XR  = Q   + (size_t)B_ * N_ * C_;      // B*NSR*C   = 1,024,000 f
  float* KVb = XR  + (size_t)B_ * NSR * C_;     // B*NSR*2C  = 2,048,000 f
  float* Ob  = KVb + (size_t)B_ * NSR * C2;     // B*N*C     = 8,192,000 f
  // total ws use: 19,456,000 floats ≈ 77.8 MB

  // 1) Q = x @ Wq + bq   (16000 x 512 x 512)
  sgemm_bias<<<dim3(250, 8), 256, 0, stream>>>(x, Wq, bq, Q, B_ * N_, C_, C_);
  // 2) xr_ln = LN(conv3d_dw(x) + sr_b)
  conv_ln_kernel<<<dim3(B_ * NSR), 512, 0, stream>>>(x, sr_w, sr_b, sr_g, sr_beta, XR);
  // 3) KV = xr_ln @ Wkv + bkv   (2000 x 1024 x 512)
  sgemm_bias<<<dim3(32, 16), 256, 0, stream>>>(XR, Wkv, bkv, KVb, B_ * NSR, C2, C_);
  // 4) O = softmax(QK^T * scale) V
  attn_kernel<<<dim3(32, B_ * NH), 256, 0, stream>>>(Q, KVb, Ob);
  // 5) O += LN(trilinear_upsample(v))
  ident_ln_add_kernel<<<dim3(B_ * N_), 512, 0, stream>>>(KVb, up_g, up_beta, Ob);
  // 6) out = O @ Wp + bp   (16000 x 512 x 512)
  sgemm_bias<<<dim3(250, 8), 256, 0, stream>>>(Ob, Wp, bp, out, B_ * N_, C_, C_);
}

// Round 2
// 736.545 us; speedup vs baseline: 1.8050x; 1.8050x over previous
//
#include <hip/hip_runtime.h>
#include <math.h>

#define B_   2
#define N_   8000
#define C_   512
#define NH   8
#define HD   64
#define DD   20
#define DR   10
#define NSR  1000
#define C2   1024
#define EPSF 1e-6f

typedef __attribute__((ext_vector_type(8))) short short8;   // 8 bf16 = 4 VGPRs
typedef __attribute__((ext_vector_type(4))) float f32x4;

__device__ __forceinline__ ushort f2bf(float f) {   // RNE float->bf16
  uint u = __float_as_uint(f);
  u += 0x7FFF + ((u >> 16) & 1);
  return (ushort)(u >> 16);
}

// ---------------- SGEMM with bias: C[M,N] = A[M,K] @ B[K,N] + bias[N] ----------------
__global__ __launch_bounds__(256) void sgemm_bias(
    const float* __restrict__ A, const float* __restrict__ Bm,
    const float* __restrict__ bias, float* __restrict__ Cm,
    int M, int Nn, int K) {
  __shared__ float As[16][65];
  __shared__ float Bs[16][65];
  const int tid = threadIdx.x;
  const int bm = blockIdx.x * 64, bn = blockIdx.y * 64;
  const int tx = tid & 15, ty = tid >> 4;
  float acc[4][4] = {};
  for (int k0 = 0; k0 < K; k0 += 16) {
    #pragma unroll
    for (int i = 0; i < 4; ++i) {
      int r = (tid >> 4) + 16 * i;
      int row = bm + r;
      float v = 0.f;
      if (row < M) v = A[(size_t)row * K + k0 + (tid & 15)];
      As[tid & 15][r] = v;
    }
    #pragma unroll
    for (int i = 0; i < 4; ++i) {
      int k = (tid >> 6) + 4 * i;
      int n = tid & 63;
      Bs[k][n] = Bm[(size_t)(k0 + k) * Nn + bn + n];
    }
    __syncthreads();
    #pragma unroll
    for (int k = 0; k < 16; ++k) {
      float a[4], b[4];
      #pragma unroll
      for (int i = 0; i < 4; ++i) a[i] = As[k][ty * 4 + i];
      #pragma unroll
      for (int j = 0; j < 4; ++j) b[j] = Bs[k][tx * 4 + j];
      #pragma unroll
      for (int i = 0; i < 4; ++i)
        #pragma unroll
        for (int j = 0; j < 4; ++j)
          acc[i][j] = fmaf(a[i], b[j], acc[i][j]);
    }
    __syncthreads();
  }
  #pragma unroll
  for (int i = 0; i < 4; ++i) {
    int row = bm + ty * 4 + i;
    if (row >= M) continue;
    #pragma unroll
    for (int j = 0; j < 4; ++j) {
      int col = bn + tx * 4 + j;
      Cm[(size_t)row * Nn + col] = acc[i][j] + bias[col];
    }
  }
}

// ---------------- depthwise conv3d k3 s2 p1 + bias + LayerNorm ----------------
__global__ __launch_bounds__(512) void conv_ln_kernel(
    const float* __restrict__ x, const float* __restrict__ sr_w,
    const float* __restrict__ sr_b, const float* __restrict__ sr_g,
    const float* __restrict__ sr_beta, float* __restrict__ xr_ln) {
  const int row = blockIdx.x;
  const int b = row / NSR, m = row % NSR;
  const int dr = m / 100, hr = (m / 10) % 10, wr = m % 10;
  const int c = threadIdx.x;
  float acc = 0.f;
  #pragma unroll
  for (int kd = 0; kd < 3; ++kd) {
    int din = 2 * dr + kd - 1;
    if (din < 0 || din >= DD) continue;
    #pragma unroll
    for (int kh = 0; kh < 3; ++kh) {
      int hin = 2 * hr + kh - 1;
      if (hin < 0 || hin >= DD) continue;
      #pragma unroll
      for (int kw = 0; kw < 3; ++kw) {
        int win = 2 * wr + kw - 1;
        if (win < 0 || win >= DD) continue;
        int nin = (din * DD + hin) * DD + win;
        acc = fmaf(x[((size_t)b * N_ + nin) * C_ + c],
                   sr_w[c * 27 + kd * 9 + kh * 3 + kw], acc);
      }
    }
  }
  acc += sr_b[c];
  float s1 = acc, s2 = acc * acc;
  #pragma unroll
  for (int off = 32; off > 0; off >>= 1) {
    s1 += __shfl_xor(s1, off, 64);
    s2 += __shfl_xor(s2, off, 64);
  }
  __shared__ float ws1[8], ws2[8];
  const int wid = threadIdx.x >> 6, lid = threadIdx.x & 63;
  if (lid == 0) { ws1[wid] = s1; ws2[wid] = s2; }
  __syncthreads();
  float t1 = 0.f, t2 = 0.f;
  #pragma unroll
  for (int i = 0; i < 8; ++i) { t1 += ws1[i]; t2 += ws2[i]; }
  float mean = t1 * (1.f / C_);
  float var = t2 * (1.f / C_) - mean * mean;
  float r = rsqrtf(var + EPSF);
  xr_ln[(size_t)row * C_ + c] = (acc - mean) * r * sr_g[c] + sr_beta[c];
}

// ---------------- MFMA flash attention ----------------
// grid = (125, B*NH), block 256 = 4 waves. Each wave: 16 query rows.
// Computes S^T = K·Q^T per 64-key step (A=K frag, B=Q frag -> D[key][query]),
// online softmax in exp2 domain, P round-trip via per-wave LDS, PV via A=P, B=Vt.
#define QSCALE (0.125f * 1.44269504088896f)  // hd^-0.5 * log2(e)
__global__ __launch_bounds__(256) void attn_mfma_kernel(
    const float* __restrict__ Q, const float* __restrict__ KV,
    float* __restrict__ O) {
  __shared__ ushort Kb[64 * 72];        // K rows: [key][d], stride 72 bf16
  __shared__ ushort Vt[64 * 72];        // V transposed: [d][key], stride 72
  __shared__ ushort Pl[4][16 * 72];     // per-wave P: [query][key], stride 72

  const int tid = threadIdx.x;
  const int bh = blockIdx.y;
  const int b = bh >> 3, h = bh & 7;
  const int wave = tid >> 6, lane = tid & 63;
  const int l = lane & 15, q = lane >> 4;
  const int qbase = blockIdx.x * 64 + wave * 16;

  union F8 { short8 v; ushort u[8]; };

  // load Q fragments (16 queries x 64 d), scale folded in
  F8 qf[2];
  {
    const float* qp = Q + ((size_t)b * N_ + qbase + l) * C_ + h * HD;
    #pragma unroll
    for (int kc = 0; kc < 2; ++kc)
      #pragma unroll
      for (int j = 0; j < 8; ++j)
        qf[kc].u[j] = f2bf(qp[q * 8 + j + 32 * kc] * QSCALE);
  }

  f32x4 o[4];
  #pragma unroll
  for (int td = 0; td < 4; ++td) o[td] = (f32x4){0.f, 0.f, 0.f, 0.f};
  float mrun = -1e30f, lrun = 0.f;

  const float* KVk = KV + (size_t)b * NSR * C2 + h * HD;        // K part
  const float* KVv = KVk + C_;                                   // V part

  for (int t0 = 0; t0 < NSR; t0 += 64) {
    __syncthreads();
    // ---- stage K rows: thread = (key = tid>>2, d-chunk = (tid&3)*16) ----
    {
      const int key = tid >> 2, dc = (tid & 3) << 4;
      const int row = min(t0 + key, NSR - 1);
      const float* src = KVk + (size_t)row * C2 + dc;
      uint pk[8];
      #pragma unroll
      for (int i = 0; i < 4; ++i) {
        float4 f = *(const float4*)(src + 4 * i);
        pk[2 * i]     = (uint)f2bf(f.x) | ((uint)f2bf(f.y) << 16);
        pk[2 * i + 1] = (uint)f2bf(f.z) | ((uint)f2bf(f.w) << 16);
      }
      uint4* dst = (uint4*)&Kb[key * 72 + dc];
      dst[0] = make_uint4(pk[0], pk[1], pk[2], pk[3]);
      dst[1] = make_uint4(pk[4], pk[5], pk[6], pk[7]);
    }
    // ---- stage V transposed: thread = (d = tid&63, key-chunk = (tid>>6)*16) ----
    {
      const int d = tid & 63, kc0 = (tid >> 6) << 4;
      uint pk[8];
      #pragma unroll
      for (int i = 0; i < 16; i += 2) {
        int r0 = min(t0 + kc0 + i, NSR - 1);
        int r1 = min(t0 + kc0 + i + 1, NSR - 1);
        float a = KVv[(size_t)r0 * C2 + d];
        float bb = KVv[(size_t)r1 * C2 + d];
        pk[i >> 1] = (uint)f2bf(a) | ((uint)f2bf(bb) << 16);
      }
      uint4* dst = (uint4*)&Vt[d * 72 + kc0];
      dst[0] = make_uint4(pk[0], pk[1], pk[2], pk[3]);
      dst[1] = make_uint4(pk[4], pk[5], pk[6], pk[7]);
    }
    __syncthreads();

    // ---- S^T tiles: D[key][query]; A = K frag, B = Q frag ----
    f32x4 s[4];
    #pragma unroll
    for (int t = 0; t < 4; ++t) s[t] = (f32x4){0.f, 0.f, 0.f, 0.f};
    #pragma unroll
    for (int kc = 0; kc < 2; ++kc) {
      #pragma unroll
      for (int t = 0; t < 4; ++t) {
        short8 af = *(const short8*)&Kb[(16 * t + l) * 72 + 8 * q + 32 * kc];
        s[t] = __builtin_amdgcn_mfma_f32_16x16x32_bf16(af, qf[kc].v, s[t], 0, 0, 0);
      }
    }
    // ---- mask last partial tile (key >= NSR) ----
    if (t0 + 64 > NSR) {
      #pragma unroll
      for (int t = 0; t < 4; ++t)
        #pragma unroll
        for (int r = 0; r < 4; ++r)
          if (t0 + 16 * t + 4 * q + r >= NSR) s[t][r] = -1e30f;
    }
    // ---- online softmax (exp2 domain); row stats at lane&15 = query ----
    float smax = -1e30f;
    #pragma unroll
    for (int t = 0; t < 4; ++t)
      #pragma unroll
      for (int r = 0; r < 4; ++r) smax = fmaxf(smax, s[t][r]);
    smax = fmaxf(smax, __shfl_xor(smax, 16, 64));
    smax = fmaxf(smax, __shfl_xor(smax, 32, 64));
    float mnew = fmaxf(mrun, smax);
    float alpha = __builtin_amdgcn_exp2f(mrun - mnew);
    float ssum = 0.f;
    #pragma unroll
    for (int t = 0; t < 4; ++t)
      #pragma unroll
      for (int r = 0; r < 4; ++r) {
        float p = __builtin_amdgcn_exp2f(s[t][r] - mnew);
        s[t][r] = p;
        ssum += p;
      }
    ssum += __shfl_xor(ssum, 16, 64);
    ssum += __shfl_xor(ssum, 32, 64);
    lrun = lrun * alpha + ssum;
    mrun = mnew;
    // ---- write P (bf16) to per-wave LDS: [query][key] ----
    #pragma unroll
    for (int t = 0; t < 4; ++t) {
      uint w0 = (uint)f2bf(s[t][0]) | ((uint)f2bf(s[t][1]) << 16);
      uint w1 = (uint)f2bf(s[t][2]) | ((uint)f2bf(s[t][3]) << 16);
      *(uint2*)&Pl[wave][l * 72 + 16 * t + 4 * q] = make_uint2(w0, w1);
    }
    // ---- rescale O by alpha (rows m = 4q+r live across lanes) ----
    float ar[4];
    #pragma unroll
    for (int r = 0; r < 4; ++r) ar[r] = __shfl(alpha, 4 * q + r, 16);
    #pragma unroll
    for (int td = 0; td < 4; ++td)
      #pragma unroll
      for (int r = 0; r < 4; ++r) o[td][r] *= ar[r];
    // ---- PV: A = P frag, B = Vt frag -> D[query][d] ----
    #pragma unroll
    for (int kc = 0; kc < 2; ++kc) {
      short8 pf = *(const short8*)&Pl[wave][l * 72 + 8 * q + 32 * kc];
      #pragma unroll
      for (int td = 0; td < 4; ++td) {
        short8 vf = *(const short8*)&Vt[(16 * td + l) * 72 + 8 * q + 32 * kc];
        o[td] = __builtin_amdgcn_mfma_f32_16x16x32_bf16(pf, vf, o[td], 0, 0, 0);
      }
    }
  }

  // ---- epilogue: divide by l, write O ----
  float linv[4];
  #pragma unroll
  for (int r = 0; r < 4; ++r) {
    float lv = __shfl(lrun, 4 * q + r, 16);
    linv[r] = 1.0f / lv;
  }
  float* op = O + ((size_t)(b * N_ + qbase)) * C_ + h * HD;
  #pragma unroll
  for (int td = 0; td < 4; ++td)
    #pragma unroll
    for (int r = 0; r < 4; ++r)
      op[(size_t)(4 * q + r) * C_ + 16 * td + l] = o[td][r] * linv[r];
}

// ---------------- trilinear upsample identity + LN + add ----------------
__global__ __launch_bounds__(512) void ident_ln_add_kernel(
    const float* __restrict__ KV, const float* __restrict__ up_g,
    const float* __restrict__ up_beta, float* __restrict__ O) {
  const int row = blockIdx.x;
  const int b = row / N_, n = row % N_;
  const int od = n / 400, oh = (n / 20) % 20, ow = n % 20;
  int i0[3], i1[3]; float w0[3], w1[3];
  int oo[3] = {od, oh, ow};
  #pragma unroll
  for (int a = 0; a < 3; ++a) {
    int t = oo[a] >> 1;
    if (oo[a] & 1) { i0[a] = t; i1[a] = (t + 1 < DR) ? t + 1 : DR - 1; w0[a] = 0.75f; w1[a] = 0.25f; }
    else           { i0[a] = (t - 1 >= 0) ? t - 1 : 0; i1[a] = t;      w0[a] = 0.25f; w1[a] = 0.75f; }
  }
  const int c = threadIdx.x;
  float val = 0.f;
  #pragma unroll
  for (int jd = 0; jd < 2; ++jd) {
    int id = jd ? i1[0] : i0[0]; float wd = jd ? w1[0] : w0[0];
    #pragma unroll
    for (int jh = 0; jh < 2; ++jh) {
      int ih = jh ? i1[1] : i0[1]; float wh = jh ? w1[1] : w0[1];
      #pragma unroll
      for (int jw = 0; jw < 2; ++jw) {
        int iw = jw ? i1[2] : i0[2]; float ww = jw ? w1[2] : w0[2];
        int mm = (id * DR + ih) * DR + iw;
        val = fmaf(wd * wh * ww, KV[((size_t)b * NSR + mm) * C2 + C_ + c], val);
      }
    }
  }
  float s1 = val, s2 = val * val;
  #pragma unroll
  for (int off = 32; off > 0; off >>= 1) {
    s1 += __shfl_xor(s1, off, 64);
    s2 += __shfl_xor(s2, off, 64);
  }
  __shared__ float ws1[8], ws2[8];
  const int wid = threadIdx.x >> 6, lid = threadIdx.x & 63;
  if (lid == 0) { ws1[wid] = s1; ws2[wid] = s2; }
  __syncthreads();
  float t1 = 0.f, t2 = 0.f;
  #pragma unroll
  for (int i = 0; i < 8; ++i) { t1 += ws1[i]; t2 += ws2[i]; }
  float mean = t1 * (1.f / C_);
  float var = t2 * (1.f / C_) - mean * mean;
  float r = rsqrtf(var + EPSF);
  O[(size_t)row * C_ + c] += (val - mean) * r * up_g[c] + up_beta[c];
}

extern "C" void kernel_launch(void* const* d_in, const int* in_sizes, int n_in,
                              void* d_out, int out_size, void* d_ws, size_t ws_size,
                              hipStream_t stream) {
  (void)in_sizes; (void)n_in; (void)out_size; (void)ws_size;
  const float* x       = (const float*)d_in[0];
  const float* Wq      = (const float*)d_in[1];
  const float* bq      = (const float*)d_in[2];
  const float* Wkv     = (const float*)d_in[3];
  const float* bkv     = (const float*)d_in[4];
  const float* sr_w    = (const float*)d_in[5];
  const float* sr_b    = (const float*)d_in[6];
  const float* sr_g    = (const float*)d_in[7];
  const float* sr_beta = (const float*)d_in[8];
  const float* up_g    = (const float*)d_in[9];
  const float* up_beta = (const float*)d_in[10];
  const float* Wp      = (const float*)d_in[11];
  const float* bp      = (const float*)d_in[12];
  float* out = (float*)d_out;

  float* Q   = (float*)d_ws;                    // B*N*C
  float* XR  = Q   + (size_t)B_ * N_ * C_;      // B*NSR*C
  float* KVb = XR  + (size_t)B_ * NSR * C_;     // B*NSR*2C
  float* Ob  = KVb + (size_t)B_ * NSR * C2;     // B*N*C

  sgemm_bias<<<dim3(250, 8), 256, 0, stream>>>(x, Wq, bq, Q, B_ * N_, C_, C_);
  conv_ln_kernel<<<dim3(B_ * NSR), 512, 0, stream>>>(x, sr_w, sr_b, sr_g, sr_beta, XR);
  sgemm_bias<<<dim3(32, 16), 256, 0, stream>>>(XR, Wkv, bkv, KVb, B_ * NSR, C2, C_);
  attn_mfma_kernel<<<dim3(125, B_ * NH), 256, 0, stream>>>(Q, KVb, Ob);
  ident_ln_add_kernel<<<dim3(B_ * N_), 512, 0, stream>>>(KVb, up_g, up_beta, Ob);
  sgemm_bias<<<dim3(250, 8), 256, 0, stream>>>(Ob, Wp, bp, out, B_ * N_, C_, C_);
}

// Round 3
// 382.929 us; speedup vs baseline: 3.4718x; 1.9235x over previous
//
#include <hip/hip_runtime.h>
#include <math.h>

#define B_   2
#define N_   8000
#define C_   512
#define NH   8
#define HD   64
#define DD   20
#define DR   10
#define NSR  1000
#define C2   1024
#define EPSF 1e-6f
#define QSCALE (0.125f * 1.44269504088896f)  // hd^-0.5 * log2(e)

typedef __attribute__((ext_vector_type(8))) short short8;   // 8 bf16 = 4 VGPRs
typedef __attribute__((ext_vector_type(4))) float f32x4;

__device__ __forceinline__ ushort f2bf(float f) {   // RNE float->bf16
  uint u = __float_as_uint(f);
  u += 0x7FFF + ((u >> 16) & 1);
  return (ushort)(u >> 16);
}

__device__ __forceinline__ void gload_lds16(const ushort* gp, ushort* lp) {
  __builtin_amdgcn_global_load_lds(
      (const __attribute__((address_space(1))) uint*)gp,
      (__attribute__((address_space(3))) uint*)lp, 16, 0, 0);
}

// ---------------- convert fp32 -> bf16, 8 elems/thread ----------------
__global__ __launch_bounds__(256) void convert_bf16_kernel(
    const float* __restrict__ src, ushort* __restrict__ dst, int n8) {
  int i = blockIdx.x * 256 + threadIdx.x;
  if (i >= n8) return;
  const float4* s = (const float4*)src + 2 * (size_t)i;
  float4 f0 = s[0], f1 = s[1];
  ushort u[8] = {f2bf(f0.x), f2bf(f0.y), f2bf(f0.z), f2bf(f0.w),
                 f2bf(f1.x), f2bf(f1.y), f2bf(f1.z), f2bf(f1.w)};
  *(uint4*)(dst + 8 * (size_t)i) = *(uint4*)u;
}

// ---------------- transpose + convert: W[K][Nn] fp32 -> Wt[Nn][K] bf16 ----------------
__global__ __launch_bounds__(256) void transpose_convert(
    const float* __restrict__ W, ushort* __restrict__ Wt, int K, int Nn) {
  __shared__ float tile[32][33];
  const int k0 = blockIdx.x * 32, n0 = blockIdx.y * 32;
  const int tx = threadIdx.x & 31, ty = threadIdx.x >> 5;  // ty 0..7
  #pragma unroll
  for (int i = 0; i < 4; ++i)
    tile[ty + 8 * i][tx] = W[(size_t)(k0 + ty + 8 * i) * Nn + n0 + tx];
  __syncthreads();
  #pragma unroll
  for (int i = 0; i < 4; ++i)
    Wt[(size_t)(n0 + ty + 8 * i) * K + k0 + tx] = f2bf(tile[tx][ty + 8 * i]);
}

// ---------------- MFMA GEMM: C[M,Nn] = A[M,K]bf16 @ Bt[Nn,K]bf16^T + bias ----------------
// 128x128 tile, BK=64, 256 threads = 4 waves (2x2 of 64x64), global_load_lds staging,
// XOR-swizzled LDS (chunk c^(row&7), rows 128B) -> conflict-free ds_read_b128.
template <bool BF16OUT>
__global__ __launch_bounds__(256) void gemm_mfma(
    const ushort* __restrict__ A, const ushort* __restrict__ Bt,
    const float* __restrict__ bias, void* __restrict__ Cout,
    int M, int Nn, int K, float oscale) {
  __shared__ __align__(16) ushort Asw[128 * 64];
  __shared__ __align__(16) ushort Bsw[128 * 64];
  const int tid = threadIdx.x;
  const int wave = tid >> 6, lane = tid & 63;
  const int l = lane & 15, q = lane >> 4;
  const int wm = (wave >> 1) * 64, wn = (wave & 1) * 64;
  const int bm = blockIdx.x * 128, bn = blockIdx.y * 128;

  const int srow = lane >> 3;                   // 0..7 within 1KB instr region
  const int schunk = (lane & 7) ^ srow;         // swizzled k-chunk (8 bf16)

  f32x4 acc[4][4];
  #pragma unroll
  for (int i = 0; i < 4; ++i)
    #pragma unroll
    for (int j = 0; j < 4; ++j) acc[i][j] = (f32x4){0.f, 0.f, 0.f, 0.f};

  for (int k0 = 0; k0 < K; k0 += 64) {
    __syncthreads();
    #pragma unroll
    for (int t = 0; t < 4; ++t) {
      const int a = wave * 4 + t;               // 0..15 -> rows 8a..8a+7
      int rowA = bm + 8 * a + srow;
      rowA = min(rowA, M - 1);
      gload_lds16(A + (size_t)rowA * K + k0 + schunk * 8, Asw + a * 512);
      const int rowB = bn + 8 * a + srow;       // Nn is multiple of 128
      gload_lds16(Bt + (size_t)rowB * K + k0 + schunk * 8, Bsw + a * 512);
    }
    __syncthreads();
    #pragma unroll
    for (int kc = 0; kc < 2; ++kc) {
      short8 af[4], bfr[4];
      const int cq = 4 * kc + q;
      #pragma unroll
      for (int i = 0; i < 4; ++i) {
        const int ra = wm + 16 * i + l;
        af[i] = *(const short8*)&Asw[ra * 64 + ((cq ^ (ra & 7)) * 8)];
        const int rb = wn + 16 * i + l;
        bfr[i] = *(const short8*)&Bsw[rb * 64 + ((cq ^ (rb & 7)) * 8)];
      }
      #pragma unroll
      for (int i = 0; i < 4; ++i)
        #pragma unroll
        for (int j = 0; j < 4; ++j)
          acc[i][j] = __builtin_amdgcn_mfma_f32_16x16x32_bf16(af[i], bfr[j], acc[i][j], 0, 0, 0);
    }
  }

  float bv[4];
  #pragma unroll
  for (int j = 0; j < 4; ++j) bv[j] = bias[bn + wn + 16 * j + l];
  #pragma unroll
  for (int i = 0; i < 4; ++i) {
    #pragma unroll
    for (int r = 0; r < 4; ++r) {
      const int row = bm + wm + 16 * i + 4 * q + r;
      if (row >= M) continue;
      #pragma unroll
      for (int j = 0; j < 4; ++j) {
        const float v = (acc[i][j][r] + bv[j]) * oscale;
        const int col = bn + wn + 16 * j + l;
        if (BF16OUT) ((ushort*)Cout)[(size_t)row * Nn + col] = f2bf(v);
        else         ((float*)Cout)[(size_t)row * Nn + col] = v;
      }
    }
  }
}

// ---------------- depthwise conv3d k3 s2 p1 + bias + LayerNorm -> bf16 ----------------
__global__ __launch_bounds__(512) void conv_ln_kernel(
    const float* __restrict__ x, const float* __restrict__ sr_w,
    const float* __restrict__ sr_b, const float* __restrict__ sr_g,
    const float* __restrict__ sr_beta, ushort* __restrict__ xr_ln) {
  const int row = blockIdx.x;
  const int b = row / NSR, m = row % NSR;
  const int dr = m / 100, hr = (m / 10) % 10, wr = m % 10;
  const int c = threadIdx.x;
  float acc = 0.f;
  #pragma unroll
  for (int kd = 0; kd < 3; ++kd) {
    int din = 2 * dr + kd - 1;
    if (din < 0 || din >= DD) continue;
    #pragma unroll
    for (int kh = 0; kh < 3; ++kh) {
      int hin = 2 * hr + kh - 1;
      if (hin < 0 || hin >= DD) continue;
      #pragma unroll
      for (int kw = 0; kw < 3; ++kw) {
        int win = 2 * wr + kw - 1;
        if (win < 0 || win >= DD) continue;
        int nin = (din * DD + hin) * DD + win;
        acc = fmaf(x[((size_t)b * N_ + nin) * C_ + c],
                   sr_w[c * 27 + kd * 9 + kh * 3 + kw], acc);
      }
    }
  }
  acc += sr_b[c];
  float s1 = acc, s2 = acc * acc;
  #pragma unroll
  for (int off = 32; off > 0; off >>= 1) {
    s1 += __shfl_xor(s1, off, 64);
    s2 += __shfl_xor(s2, off, 64);
  }
  __shared__ float ws1[8], ws2[8];
  const int wid = threadIdx.x >> 6, lid = threadIdx.x & 63;
  if (lid == 0) { ws1[wid] = s1; ws2[wid] = s2; }
  __syncthreads();
  float t1 = 0.f, t2 = 0.f;
  #pragma unroll
  for (int i = 0; i < 8; ++i) { t1 += ws1[i]; t2 += ws2[i]; }
  float mean = t1 * (1.f / C_);
  float var = t2 * (1.f / C_) - mean * mean;
  float r = rsqrtf(var + EPSF);
  xr_ln[(size_t)row * C_ + c] = f2bf((acc - mean) * r * sr_g[c] + sr_beta[c]);
}

// ---------------- MFMA flash attention (Q pre-scaled bf16) ----------------
__global__ __launch_bounds__(256) void attn_mfma_kernel(
    const ushort* __restrict__ Qb, const float* __restrict__ KV,
    float* __restrict__ O) {
  __shared__ ushort Kb[64 * 72];
  __shared__ ushort Vt[64 * 72];
  __shared__ ushort Pl[4][16 * 72];

  const int tid = threadIdx.x;
  const int bh = blockIdx.y;
  const int b = bh >> 3, h = bh & 7;
  const int wave = tid >> 6, lane = tid & 63;
  const int l = lane & 15, q = lane >> 4;
  const int qbase = blockIdx.x * 64 + wave * 16;

  short8 qf[2];
  {
    const ushort* qp = Qb + ((size_t)b * N_ + qbase + l) * C_ + h * HD;
    qf[0] = *(const short8*)(qp + 8 * q);
    qf[1] = *(const short8*)(qp + 8 * q + 32);
  }

  f32x4 o[4];
  #pragma unroll
  for (int td = 0; td < 4; ++td) o[td] = (f32x4){0.f, 0.f, 0.f, 0.f};
  float mrun = -1e30f, lrun = 0.f;

  const float* KVk = KV + (size_t)b * NSR * C2 + h * HD;
  const float* KVv = KVk + C_;

  for (int t0 = 0; t0 < NSR; t0 += 64) {
    __syncthreads();
    {
      const int key = tid >> 2, dc = (tid & 3) << 4;
      const int row = min(t0 + key, NSR - 1);
      const float* src = KVk + (size_t)row * C2 + dc;
      uint pk[8];
      #pragma unroll
      for (int i = 0; i < 4; ++i) {
        float4 f = *(const float4*)(src + 4 * i);
        pk[2 * i]     = (uint)f2bf(f.x) | ((uint)f2bf(f.y) << 16);
        pk[2 * i + 1] = (uint)f2bf(f.z) | ((uint)f2bf(f.w) << 16);
      }
      uint4* dst = (uint4*)&Kb[key * 72 + dc];
      dst[0] = make_uint4(pk[0], pk[1], pk[2], pk[3]);
      dst[1] = make_uint4(pk[4], pk[5], pk[6], pk[7]);
    }
    {
      const int d = tid & 63, kc0 = (tid >> 6) << 4;
      uint pk[8];
      #pragma unroll
      for (int i = 0; i < 16; i += 2) {
        int r0 = min(t0 + kc0 + i, NSR - 1);
        int r1 = min(t0 + kc0 + i + 1, NSR - 1);
        float a = KVv[(size_t)r0 * C2 + d];
        float bb = KVv[(size_t)r1 * C2 + d];
        pk[i >> 1] = (uint)f2bf(a) | ((uint)f2bf(bb) << 16);
      }
      uint4* dst = (uint4*)&Vt[d * 72 + kc0];
      dst[0] = make_uint4(pk[0], pk[1], pk[2], pk[3]);
      dst[1] = make_uint4(pk[4], pk[5], pk[6], pk[7]);
    }
    __syncthreads();

    f32x4 s[4];
    #pragma unroll
    for (int t = 0; t < 4; ++t) s[t] = (f32x4){0.f, 0.f, 0.f, 0.f};
    #pragma unroll
    for (int kc = 0; kc < 2; ++kc) {
      #pragma unroll
      for (int t = 0; t < 4; ++t) {
        short8 af = *(const short8*)&Kb[(16 * t + l) * 72 + 8 * q + 32 * kc];
        s[t] = __builtin_amdgcn_mfma_f32_16x16x32_bf16(af, qf[kc], s[t], 0, 0, 0);
      }
    }
    if (t0 + 64 > NSR) {
      #pragma unroll
      for (int t = 0; t < 4; ++t)
        #pragma unroll
        for (int r = 0; r < 4; ++r)
          if (t0 + 16 * t + 4 * q + r >= NSR) s[t][r] = -1e30f;
    }
    float smax = -1e30f;
    #pragma unroll
    for (int t = 0; t < 4; ++t)
      #pragma unroll
      for (int r = 0; r < 4; ++r) smax = fmaxf(smax, s[t][r]);
    smax = fmaxf(smax, __shfl_xor(smax, 16, 64));
    smax = fmaxf(smax, __shfl_xor(smax, 32, 64));
    float mnew = fmaxf(mrun, smax);
    float alpha = __builtin_amdgcn_exp2f(mrun - mnew);
    float ssum = 0.f;
    #pragma unroll
    for (int t = 0; t < 4; ++t)
      #pragma unroll
      for (int r = 0; r < 4; ++r) {
        float p = __builtin_amdgcn_exp2f(s[t][r] - mnew);
        s[t][r] = p;
        ssum += p;
      }
    ssum += __shfl_xor(ssum, 16, 64);
    ssum += __shfl_xor(ssum, 32, 64);
    lrun = lrun * alpha + ssum;
    mrun = mnew;
    #pragma unroll
    for (int t = 0; t < 4; ++t) {
      uint w0 = (uint)f2bf(s[t][0]) | ((uint)f2bf(s[t][1]) << 16);
      uint w1 = (uint)f2bf(s[t][2]) | ((uint)f2bf(s[t][3]) << 16);
      *(uint2*)&Pl[wave][l * 72 + 16 * t + 4 * q] = make_uint2(w0, w1);
    }
    float ar[4];
    #pragma unroll
    for (int r = 0; r < 4; ++r) ar[r] = __shfl(alpha, 4 * q + r, 16);
    #pragma unroll
    for (int td = 0; td < 4; ++td)
      #pragma unroll
      for (int r = 0; r < 4; ++r) o[td][r] *= ar[r];
    #pragma unroll
    for (int kc = 0; kc < 2; ++kc) {
      short8 pf = *(const short8*)&Pl[wave][l * 72 + 8 * q + 32 * kc];
      #pragma unroll
      for (int td = 0; td < 4; ++td) {
        short8 vf = *(const short8*)&Vt[(16 * td + l) * 72 + 8 * q + 32 * kc];
        o[td] = __builtin_amdgcn_mfma_f32_16x16x32_bf16(pf, vf, o[td], 0, 0, 0);
      }
    }
  }

  float linv[4];
  #pragma unroll
  for (int r = 0; r < 4; ++r) {
    float lv = __shfl(lrun, 4 * q + r, 16);
    linv[r] = 1.0f / lv;
  }
  float* op = O + ((size_t)(b * N_ + qbase)) * C_ + h * HD;
  #pragma unroll
  for (int td = 0; td < 4; ++td)
    #pragma unroll
    for (int r = 0; r < 4; ++r)
      op[(size_t)(4 * q + r) * C_ + 16 * td + l] = o[td][r] * linv[r];
}

// ---------------- trilinear upsample identity + LN + add -> bf16 out-proj input ----------------
__global__ __launch_bounds__(512) void ident_ln_add_kernel(
    const float* __restrict__ KV, const float* __restrict__ up_g,
    const float* __restrict__ up_beta, const float* __restrict__ O,
    ushort* __restrict__ Obb) {
  const int row = blockIdx.x;
  const int b = row / N_, n = row % N_;
  const int od = n / 400, oh = (n / 20) % 20, ow = n % 20;
  int i0[3], i1[3]; float w0[3], w1[3];
  int oo[3] = {od, oh, ow};
  #pragma unroll
  for (int a = 0; a < 3; ++a) {
    int t = oo[a] >> 1;
    if (oo[a] & 1) { i0[a] = t; i1[a] = (t + 1 < DR) ? t + 1 : DR - 1; w0[a] = 0.75f; w1[a] = 0.25f; }
    else           { i0[a] = (t - 1 >= 0) ? t - 1 : 0; i1[a] = t;      w0[a] = 0.25f; w1[a] = 0.75f; }
  }
  const int c = threadIdx.x;
  float val = 0.f;
  #pragma unroll
  for (int jd = 0; jd < 2; ++jd) {
    int id = jd ? i1[0] : i0[0]; float wd = jd ? w1[0] : w0[0];
    #pragma unroll
    for (int jh = 0; jh < 2; ++jh) {
      int ih = jh ? i1[1] : i0[1]; float wh = jh ? w1[1] : w0[1];
      #pragma unroll
      for (int jw = 0; jw < 2; ++jw) {
        int iw = jw ? i1[2] : i0[2]; float ww = jw ? w1[2] : w0[2];
        int mm = (id * DR + ih) * DR + iw;
        val = fmaf(wd * wh * ww, KV[((size_t)b * NSR + mm) * C2 + C_ + c], val);
      }
    }
  }
  float s1 = val, s2 = val * val;
  #pragma unroll
  for (int off = 32; off > 0; off >>= 1) {
    s1 += __shfl_xor(s1, off, 64);
    s2 += __shfl_xor(s2, off, 64);
  }
  __shared__ float ws1[8], ws2[8];
  const int wid = threadIdx.x >> 6, lid = threadIdx.x & 63;
  if (lid == 0) { ws1[wid] = s1; ws2[wid] = s2; }
  __syncthreads();
  float t1 = 0.f, t2 = 0.f;
  #pragma unroll
  for (int i = 0; i < 8; ++i) { t1 += ws1[i]; t2 += ws2[i]; }
  float mean = t1 * (1.f / C_);
  float var = t2 * (1.f / C_) - mean * mean;
  float r = rsqrtf(var + EPSF);
  Obb[(size_t)row * C_ + c] =
      f2bf(O[(size_t)row * C_ + c] + (val - mean) * r * up_g[c] + up_beta[c]);
}

extern "C" void kernel_launch(void* const* d_in, const int* in_sizes, int n_in,
                              void* d_out, int out_size, void* d_ws, size_t ws_size,
                              hipStream_t stream) {
  (void)in_sizes; (void)n_in; (void)out_size; (void)ws_size;
  const float* x       = (const float*)d_in[0];
  const float* Wq      = (const float*)d_in[1];
  const float* bq      = (const float*)d_in[2];
  const float* Wkv     = (const float*)d_in[3];
  const float* bkv     = (const float*)d_in[4];
  const float* sr_w    = (const float*)d_in[5];
  const float* sr_b    = (const float*)d_in[6];
  const float* sr_g    = (const float*)d_in[7];
  const float* sr_beta = (const float*)d_in[8];
  const float* up_g    = (const float*)d_in[9];
  const float* up_beta = (const float*)d_in[10];
  const float* Wp      = (const float*)d_in[11];
  const float* bp      = (const float*)d_in[12];
  float* out = (float*)d_out;

  // workspace layout (77.9 MB): floats first, then bf16; Obb aliases xb (xb dead after q-proj)
  float*  KVb  = (float*)d_ws;                  // 2,048,000 f
  float*  Ob   = KVb + 2048000;                 // 8,192,000 f
  ushort* xb   = (ushort*)(Ob + 8192000);       // 8,192,000 us (aliased by Obb later)
  ushort* Qb   = xb + 8192000;                  // 8,192,000 us
  ushort* XRb  = Qb + 8192000;                  // 1,024,000 us
  ushort* Wqt  = XRb + 1024000;                 //   262,144 us
  ushort* Wkvt = Wqt + 262144;                  //   524,288 us
  ushort* Wpt  = Wkvt + 524288;                 //   262,144 us
  ushort* Obb  = xb;

  // 0) dtype prep
  convert_bf16_kernel<<<dim3(4000), 256, 0, stream>>>(x, xb, B_ * N_ * C_ / 8);
  transpose_convert<<<dim3(16, 16), 256, 0, stream>>>(Wq, Wqt, C_, C_);
  transpose_convert<<<dim3(16, 32), 256, 0, stream>>>(Wkv, Wkvt, C_, C2);
  transpose_convert<<<dim3(16, 16), 256, 0, stream>>>(Wp, Wpt, C_, C_);
  // 1) Qb = bf16((x @ Wq + bq) * qscale)
  gemm_mfma<true><<<dim3(125, 4), 256, 0, stream>>>(xb, Wqt, bq, Qb, B_ * N_, C_, C_, QSCALE);
  // 2) XRb = bf16(LN(conv3d_dw(x) + sr_b))
  conv_ln_kernel<<<dim3(B_ * NSR), 512, 0, stream>>>(x, sr_w, sr_b, sr_g, sr_beta, XRb);
  // 3) KV = XRb @ Wkv + bkv (fp32)
  gemm_mfma<false><<<dim3(16, 8), 256, 0, stream>>>(XRb, Wkvt, bkv, KVb, B_ * NSR, C2, C_, 1.0f);
  // 4) O = softmax(QK^T) V
  attn_mfma_kernel<<<dim3(125, B_ * NH), 256, 0, stream>>>(Qb, KVb, Ob);
  // 5) Obb = bf16(O + LN(upsample(v)))
  ident_ln_add_kernel<<<dim3(B_ * N_), 512, 0, stream>>>(KVb, up_g, up_beta, Ob, Obb);
  // 6) out = Obb @ Wp + bp (fp32)
  gemm_mfma<false><<<dim3(125, 4), 256, 0, stream>>>(Obb, Wpt, bp, out, B_ * N_, C_, C_, 1.0f);
}